// Round 3
// baseline (2901.450 us; speedup 1.0000x reference)
//
#include <hip/hip_runtime.h>
#include <hip/hip_bf16.h>
#include <math.h>

typedef unsigned short u16;
typedef __hip_bfloat16 bf16;
typedef __bf16 bf16x8 __attribute__((ext_vector_type(8)));
typedef float f32x4 __attribute__((ext_vector_type(4)));

#define B_DIM 2048
#define Z_DIM 512
#define H_DIM 384
#define G_DIM 1536   // 4H
#define T_FRM 32
#define N_STEP 31
#define W_RES 0.2f

__device__ __forceinline__ u16 f2b(float f) {
    bf16 h = __float2bfloat16(f);
    return __builtin_bit_cast(u16, h);
}

typedef const __attribute__((address_space(1))) void* gas1_t;
typedef __attribute__((address_space(3))) void* las3_t;

__device__ __forceinline__ void gld_lds16(const void* g, void* l) {
    // async global->LDS, 16B per lane; HW dest = wave-uniform base + lane*16
    __builtin_amdgcn_global_load_lds((gas1_t)g, (las3_t)l, 16, 0, 0);
}

// 128x128 C-tile, 256 threads (4 waves, 2x2), mfma_f32_16x16x32_bf16, BK=32.
// A: [M,K] bf16 row-major (lda), rows at arow0.
// B: [N,K] bf16 row-major (ldb) -> computes A@B^T tile.
__device__ __forceinline__ void gemm_seg(const u16* __restrict__ A, int lda,
                                         const u16* __restrict__ B, int ldb,
                                         int arow0, int bcol0, int kch,
                                         u16* Asm, u16* Bsm, f32x4 acc[4][4])
{
    const int tid  = threadIdx.x;
    const int lane = tid & 63;
    const int wr   = ((tid >> 7) & 1) * 64;   // wave row offset
    const int wc   = ((tid >> 6) & 1) * 64;   // wave col offset
    const int l15  = lane & 15;
    const int q    = lane >> 4;
    const int srow = tid >> 2;                // staging: 4 lanes/row, 8 elems each
    const int sk   = (tid & 3) * 8;
    const u16* Ab = A + (size_t)(arow0 + srow) * lda + sk;
    const u16* Bb = B + (size_t)(bcol0 + srow) * ldb + sk;
    const size_t rstepA = (size_t)64 * lda;
    const size_t rstepB = (size_t)64 * ldb;
    u16* Al0 = Asm + tid * 8;
    u16* Bl0 = Bsm + tid * 8;

    for (int kt = 0; kt < kch; ++kt) {
        const int ko = kt * 32;
        gld_lds16(Ab + ko,          Al0);
        gld_lds16(Ab + rstepA + ko, Al0 + 2048);
        gld_lds16(Bb + ko,          Bl0);
        gld_lds16(Bb + rstepB + ko, Bl0 + 2048);
        __syncthreads();   // drains vmcnt -> LDS tiles ready
        bf16x8 av[4], bv[4];
#pragma unroll
        for (int i = 0; i < 4; ++i) {
            av[i] = *(const bf16x8*)(Asm + (wr + i * 16 + l15) * 32 + q * 8);
            bv[i] = *(const bf16x8*)(Bsm + (wc + i * 16 + l15) * 32 + q * 8);
        }
#pragma unroll
        for (int i = 0; i < 4; ++i)
#pragma unroll
            for (int j = 0; j < 4; ++j)
                acc[i][j] = __builtin_amdgcn_mfma_f32_16x16x32_bf16(av[i], bv[j], acc[i][j], 0, 0, 0);
        __syncthreads();   // all waves done reading before next stage
    }
}

// gates = A1@B1^T (+ A2@B2^T) + bias1 + bias2 -> fp32 [2048,1536]
__global__ __launch_bounds__(256, 2) void k_gates(
    const u16* __restrict__ A1, const u16* __restrict__ B1, int ld1, int k1,
    const u16* __restrict__ A2, const u16* __restrict__ B2, int lda2, int ldb2, int k2,
    const float* __restrict__ bias1, const float* __restrict__ bias2,
    float* __restrict__ C)
{
    __shared__ __attribute__((aligned(16))) u16 Asm[128 * 32];
    __shared__ __attribute__((aligned(16))) u16 Bsm[128 * 32];
    f32x4 acc[4][4];
    const f32x4 z4 = {0.f, 0.f, 0.f, 0.f};
#pragma unroll
    for (int i = 0; i < 4; ++i)
#pragma unroll
        for (int j = 0; j < 4; ++j) acc[i][j] = z4;

    const int row0 = blockIdx.x * 128;
    const int col0 = blockIdx.y * 128;
    gemm_seg(A1, ld1, B1, ld1, row0, col0, k1, Asm, Bsm, acc);
    if (k2 > 0) gemm_seg(A2, lda2, B2, ldb2, row0, col0, k2, Asm, Bsm, acc);

    const int lane = threadIdx.x & 63;
    const int wr = ((threadIdx.x >> 7) & 1) * 64;
    const int wc = ((threadIdx.x >> 6) & 1) * 64;
    const int l15 = lane & 15;
    const int q4 = (lane >> 4) * 4;
#pragma unroll
    for (int j = 0; j < 4; ++j) {
        const int col = col0 + wc + j * 16 + l15;
        const float bias = bias1[col] + bias2[col];
#pragma unroll
        for (int i = 0; i < 4; ++i) {
            const int row = row0 + wr + i * 16 + q4;
            float* Cp = C + (size_t)row * G_DIM + col;
#pragma unroll
            for (int r = 0; r < 4; ++r)
                Cp[(size_t)r * G_DIM] = acc[i][j][r] + bias;
        }
    }
}

// LSTM cell elementwise over [2048,384]; h (bf16 operand), c (fp32 master),
// decoder steps (s>=0) also write per-step [h|c] bf16 block hcs [2048,768].
__global__ void k_lstm(const float* __restrict__ gates, float* __restrict__ c_fp,
                       u16* __restrict__ h_bf, u16* __restrict__ hcs, int s, int czero)
{
    const int i = blockIdx.x * 256 + threadIdx.x;   // < 2048*384
    const int m = i / H_DIM;
    const int j = i - m * H_DIM;
    const float* gr = gates + (size_t)m * G_DIM + j;
    const float gi = gr[0], gf = gr[H_DIM], gg = gr[2 * H_DIM], go = gr[3 * H_DIM];
    const float c  = czero ? 0.f : c_fp[i];
    const float si = 1.f / (1.f + __expf(-gi));
    const float sf = 1.f / (1.f + __expf(-gf));
    const float so = 1.f / (1.f + __expf(-go));
    const float c2 = sf * c + si * tanhf(gg);
    const float h2 = so * tanhf(c2);
    c_fp[i] = c2;
    h_bf[i] = f2b(h2);
    if (s >= 0) {
        hcs[(size_t)m * (2 * H_DIM) + j]         = f2b(h2);
        hcs[(size_t)m * (2 * H_DIM) + H_DIM + j] = f2b(c2);
    }
}

// out_new = out + 0.2*tanh(h2@wT^T + b); fp32 master + bf16 operand + fp32 d_out slices
__global__ __launch_bounds__(256, 2) void k_out(
    const u16* __restrict__ hbf, const u16* __restrict__ wT, const float* __restrict__ bias,
    float* __restrict__ out_fp, u16* __restrict__ out_bf,
    float* __restrict__ outsec, float* __restrict__ esec, int ts)
{
    __shared__ __attribute__((aligned(16))) u16 Asm[128 * 32];
    __shared__ __attribute__((aligned(16))) u16 Bsm[128 * 32];
    f32x4 acc[4][4];
    const f32x4 z4 = {0.f, 0.f, 0.f, 0.f};
#pragma unroll
    for (int i = 0; i < 4; ++i)
#pragma unroll
        for (int j = 0; j < 4; ++j) acc[i][j] = z4;

    const int row0 = blockIdx.x * 128;
    const int col0 = blockIdx.y * 128;
    gemm_seg(hbf, H_DIM, wT, H_DIM, row0, col0, H_DIM / 32, Asm, Bsm, acc);

    const int lane = threadIdx.x & 63;
    const int wr = ((threadIdx.x >> 7) & 1) * 64;
    const int wc = ((threadIdx.x >> 6) & 1) * 64;
    const int l15 = lane & 15;
    const int q4 = (lane >> 4) * 4;
#pragma unroll
    for (int j = 0; j < 4; ++j) {
        const int col = col0 + wc + j * 16 + l15;
        const float bv = bias[col];
#pragma unroll
        for (int i = 0; i < 4; ++i) {
            const int row = row0 + wr + i * 16 + q4;
#pragma unroll
            for (int r = 0; r < 4; ++r) {
                const int rr = row + r;
                const size_t idx = (size_t)rr * Z_DIM + col;
                const float v = acc[i][j][r] + bv;
                const float onew = out_fp[idx] + W_RES * tanhf(v);
                out_fp[idx] = onew;
                out_bf[idx] = f2b(onew);
                outsec[((size_t)rr * T_FRM + ts) * Z_DIM + col] = onew;
                if (ts <= 30)
                    esec[((size_t)rr * N_STEP + ts) * Z_DIM + col] = onew;
            }
        }
    }
}

// fc1: t1(bf16 [2048,512]) = relu(hcs @ fc1w^T + fc1b)
__global__ __launch_bounds__(256, 2) void k_fc1(
    const u16* __restrict__ A, const u16* __restrict__ B, const float* __restrict__ bias,
    u16* __restrict__ C)
{
    __shared__ __attribute__((aligned(16))) u16 Asm[128 * 32];
    __shared__ __attribute__((aligned(16))) u16 Bsm[128 * 32];
    f32x4 acc[4][4];
    const f32x4 z4 = {0.f, 0.f, 0.f, 0.f};
#pragma unroll
    for (int i = 0; i < 4; ++i)
#pragma unroll
        for (int j = 0; j < 4; ++j) acc[i][j] = z4;

    const int row0 = blockIdx.x * 128;
    const int col0 = blockIdx.y * 128;
    gemm_seg(A, 2 * H_DIM, B, 2 * H_DIM, row0, col0, 2 * H_DIM / 32, Asm, Bsm, acc);

    const int lane = threadIdx.x & 63;
    const int wr = ((threadIdx.x >> 7) & 1) * 64;
    const int wc = ((threadIdx.x >> 6) & 1) * 64;
    const int l15 = lane & 15;
    const int q4 = (lane >> 4) * 4;
#pragma unroll
    for (int j = 0; j < 4; ++j) {
        const int col = col0 + wc + j * 16 + l15;
        const float bv = bias[col];
#pragma unroll
        for (int i = 0; i < 4; ++i) {
            const int row = row0 + wr + i * 16 + q4;
#pragma unroll
            for (int r = 0; r < 4; ++r)
                C[(size_t)(row + r) * Z_DIM + col] = f2b(fmaxf(acc[i][j][r] + bv, 0.f));
        }
    }
}

// fc2: erec rows for step s (fp32): C[row*15872 + col] = t1 @ fc2w^T + fc2b
__global__ __launch_bounds__(256, 2) void k_fc2(
    const u16* __restrict__ A, const u16* __restrict__ B, const float* __restrict__ bias,
    float* __restrict__ C)
{
    __shared__ __attribute__((aligned(16))) u16 Asm[128 * 32];
    __shared__ __attribute__((aligned(16))) u16 Bsm[128 * 32];
    f32x4 acc[4][4];
    const f32x4 z4 = {0.f, 0.f, 0.f, 0.f};
#pragma unroll
    for (int i = 0; i < 4; ++i)
#pragma unroll
        for (int j = 0; j < 4; ++j) acc[i][j] = z4;

    const int row0 = blockIdx.x * 128;
    const int col0 = blockIdx.y * 128;
    gemm_seg(A, Z_DIM, B, Z_DIM, row0, col0, Z_DIM / 32, Asm, Bsm, acc);

    const int lane = threadIdx.x & 63;
    const int wr = ((threadIdx.x >> 7) & 1) * 64;
    const int wc = ((threadIdx.x >> 6) & 1) * 64;
    const int l15 = lane & 15;
    const int q4 = (lane >> 4) * 4;
#pragma unroll
    for (int j = 0; j < 4; ++j) {
        const int col = col0 + wc + j * 16 + l15;
        const float bv = bias[col];
#pragma unroll
        for (int i = 0; i < 4; ++i) {
            const int row = row0 + wr + i * 16 + q4;
#pragma unroll
            for (int r = 0; r < 4; ++r)
                C[(size_t)(row + r) * (N_STEP * Z_DIM) + col] = acc[i][j][r] + bv;
        }
    }
}

// fp32 -> bf16 elementwise convert (one-shot, weights)
__global__ void k_cvt(const float* __restrict__ src, u16* __restrict__ dst, int n)
{
    const int i = blockIdx.x * 256 + threadIdx.x;
    if (i < n) dst[i] = f2b(src[i]);
}

// init: out_fp = z, out_bf = bf16(z); out time-slice 0 = z; e time-slice 0 = z (fp32)
__global__ void k_init(const float* __restrict__ z, float* __restrict__ out_fp,
                       u16* __restrict__ out_bf, float* __restrict__ outsec,
                       float* __restrict__ esec)
{
    const int i = blockIdx.x * 256 + threadIdx.x;   // < 2048*512
    const int m = i >> 9;
    const int n = i & 511;
    const float zv = z[i];
    out_fp[i] = zv;
    out_bf[i] = f2b(zv);
    outsec[((size_t)m * T_FRM) * Z_DIM + n] = zv;
    esec[((size_t)m * N_STEP) * Z_DIM + n] = zv;
}

// wT[n][k] = bf16(w[k][n])  (w: fp32 [384,512] -> wT: bf16 [512,384])
__global__ void k_trw(const float* __restrict__ w, u16* __restrict__ wT)
{
    const int i = blockIdx.x * 256 + threadIdx.x;   // < 384*512
    const int k = i >> 9;
    const int n = i & 511;
    wT[(size_t)n * H_DIM + k] = f2b(w[i]);
}

extern "C" void kernel_launch(void* const* d_in, const int* in_sizes, int n_in,
                              void* d_out, int out_size, void* d_ws, size_t ws_size,
                              hipStream_t stream)
{
    const float* z       = (const float*)d_in[0];
    const float* Wih_enc = (const float*)d_in[1];
    // d_in[2] = Whh_enc: multiplied by h=0 in the encoder -> unused
    const float* bih_enc = (const float*)d_in[3];
    const float* bhh_enc = (const float*)d_in[4];
    const float* Wih  = (const float*)d_in[5];
    const float* Whh  = (const float*)d_in[6];
    const float* bih  = (const float*)d_in[7];
    const float* bhh  = (const float*)d_in[8];
    const float* w    = (const float*)d_in[9];
    const float* bvec = (const float*)d_in[10];
    const float* fc1w = (const float*)d_in[11];
    const float* fc1b = (const float*)d_in[12];
    const float* fc2w = (const float*)d_in[13];
    const float* fc2b = (const float*)d_in[14];
    // n_frame fixed at 32 (cannot read device scalar during graph capture)

    float* outsec = (float*)d_out;                                  // [2048*32, 512]
    float* esec   = outsec + (size_t)B_DIM * T_FRM * Z_DIM;         // [2048*31, 512]
    float* erec   = esec + (size_t)B_DIM * N_STEP * Z_DIM;          // [2048*31, 512]

    // Fixed workspace plan, ~35 MiB total.
    char* ws = (char*)d_ws;
    size_t off = 0;
    auto alloc = [&](size_t bytes) -> char* {
        char* p = ws + off;
        off += (bytes + 255) & ~(size_t)255;
        return p;
    };
    float* gates   = (float*)alloc((size_t)B_DIM * G_DIM * 4);       // 12.6 MB
    float* c_fp    = (float*)alloc((size_t)B_DIM * H_DIM * 4);       //  3.1 MB
    float* out_fp  = (float*)alloc((size_t)B_DIM * Z_DIM * 4);       //  4.2 MB
    u16*   out_bf  = (u16*)  alloc((size_t)B_DIM * Z_DIM * 2);       //  2.1 MB
    u16*   h_bf    = (u16*)  alloc((size_t)B_DIM * H_DIM * 2);       //  1.6 MB
    u16*   wT      = (u16*)  alloc((size_t)Z_DIM * H_DIM * 2);       //  0.4 MB
    u16*   hcs     = (u16*)  alloc((size_t)B_DIM * 2 * H_DIM * 2);   //  3.1 MB
    u16*   t1      = (u16*)  alloc((size_t)B_DIM * Z_DIM * 2);       //  2.1 MB
    u16*   Wenc_bf = (u16*)  alloc((size_t)G_DIM * Z_DIM * 2);       //  1.6 MB
    u16*   Wih_bf  = (u16*)  alloc((size_t)G_DIM * Z_DIM * 2);       //  1.6 MB
    u16*   Whh_bf  = (u16*)  alloc((size_t)G_DIM * H_DIM * 2);       //  1.2 MB
    u16*   fc1w_bf = (u16*)  alloc((size_t)Z_DIM * 2 * H_DIM * 2);   //  0.8 MB
    u16*   fc2w_bf = (u16*)  alloc((size_t)Z_DIM * Z_DIM * 2);       //  0.5 MB

    const dim3 blk(256);
    // one-shot weight conversions
    k_cvt<<<G_DIM * Z_DIM / 256, blk, 0, stream>>>(Wih_enc, Wenc_bf, G_DIM * Z_DIM);
    k_cvt<<<G_DIM * Z_DIM / 256, blk, 0, stream>>>(Wih, Wih_bf, G_DIM * Z_DIM);
    k_cvt<<<G_DIM * H_DIM / 256, blk, 0, stream>>>(Whh, Whh_bf, G_DIM * H_DIM);
    k_cvt<<<Z_DIM * 2 * H_DIM / 256, blk, 0, stream>>>(fc1w, fc1w_bf, Z_DIM * 2 * H_DIM);
    k_cvt<<<Z_DIM * Z_DIM / 256, blk, 0, stream>>>(fc2w, fc2w_bf, Z_DIM * Z_DIM);
    k_trw<<<H_DIM * Z_DIM / 256, blk, 0, stream>>>(w, wT);
    k_init<<<B_DIM * Z_DIM / 256, blk, 0, stream>>>(z, out_fp, out_bf, outsec, esec);

    // encoder: gates = z @ Wih_enc^T + bih_enc + bhh_enc  (h=0 => Whh_enc term vanishes)
    k_gates<<<dim3(16, 12), blk, 0, stream>>>(out_bf, Wenc_bf, Z_DIM, Z_DIM / 32,
                                              nullptr, nullptr, 0, 0, 0,
                                              bih_enc, bhh_enc, gates);
    k_lstm<<<B_DIM * H_DIM / 256, blk, 0, stream>>>(gates, c_fp, h_bf, hcs, -1, 1);

    for (int s = 0; s < N_STEP; ++s) {
        k_gates<<<dim3(16, 12), blk, 0, stream>>>(out_bf, Wih_bf, Z_DIM, Z_DIM / 32,
                                                  h_bf, Whh_bf, H_DIM, H_DIM, H_DIM / 32,
                                                  bih, bhh, gates);
        k_lstm<<<B_DIM * H_DIM / 256, blk, 0, stream>>>(gates, c_fp, h_bf, hcs, s, 0);
        k_out<<<dim3(16, 4), blk, 0, stream>>>(h_bf, wT, bvec, out_fp, out_bf,
                                               outsec, esec, s + 1);
        k_fc1<<<dim3(16, 4), blk, 0, stream>>>(hcs, fc1w_bf, fc1b, t1);
        k_fc2<<<dim3(16, 4), blk, 0, stream>>>(t1, fc2w_bf, fc2b,
                                               erec + (size_t)s * Z_DIM);
    }
}